// Round 3
// baseline (1901.172 us; speedup 1.0000x reference)
//
#include <hip/hip_runtime.h>
#include <cstdint>
#include <cstddef>

// Problem constants (EmformerBlock): B=4, S=2560, D=512, H=8, DK=64, F=2048
#define B_    4
#define S_    2560
#define D_    512
#define H_    8
#define DK_   64
#define F_    2048
#define NTOK  (B_ * S_)   // 10240

// ---------------------------------------------------------------------------
// LayerNorm over D=512, one row per block (256 threads, 2 floats/thread).
// Optional residual input (added before norm) and optional pre-norm output.
// NOTE: `out` may alias `res` (per-thread elementwise read-before-write).
// ---------------------------------------------------------------------------
__global__ __launch_bounds__(256) void ln_kernel(
    const float* __restrict__ in, const float* __restrict__ res,
    const float* __restrict__ gamma, const float* __restrict__ beta,
    float* __restrict__ out, float* __restrict__ pre_out)
{
  const int row = blockIdx.x;
  const int t   = threadIdx.x;
  const size_t base = (size_t)row * D_;

  float2 v = *(const float2*)(in + base + t * 2);
  if (res) {
    float2 r = *(const float2*)(res + base + t * 2);
    v.x += r.x; v.y += r.y;
  }
  if (pre_out) *(float2*)(pre_out + base + t * 2) = v;

  float s1 = v.x + v.y;
  float s2 = v.x * v.x + v.y * v.y;
#pragma unroll
  for (int off = 32; off > 0; off >>= 1) {
    s1 += __shfl_down(s1, off);
    s2 += __shfl_down(s2, off);
  }
  __shared__ float a1[4], a2[4];
  const int wid = t >> 6, lane = t & 63;
  if (lane == 0) { a1[wid] = s1; a2[wid] = s2; }
  __syncthreads();
  const float S1 = a1[0] + a1[1] + a1[2] + a1[3];
  const float S2 = a2[0] + a2[1] + a2[2] + a2[3];
  const float mu  = S1 * (1.0f / D_);
  const float var = S2 * (1.0f / D_) - mu * mu;
  const float inv = rsqrtf(var + 1e-5f);

  float2 g = *(const float2*)(gamma + t * 2);
  float2 b = *(const float2*)(beta  + t * 2);
  float2 o;
  o.x = (v.x - mu) * inv * g.x + b.x;
  o.y = (v.y - mu) * inv * g.y + b.y;
  *(float2*)(out + base + t * 2) = o;
}

// ---------------------------------------------------------------------------
// Generic fp32 tiled GEMM: C[M,N] = A[M,K] @ Bm[K,N] + bias[N]
// BM=BN=128, BK=16, 256 threads, 8x8 microtile. All dims divide evenly here.
// ---------------------------------------------------------------------------
__global__ __launch_bounds__(256) void gemm_bias_kernel(
    const float* __restrict__ A, const float* __restrict__ Bm,
    const float* __restrict__ bias, float* __restrict__ C,
    int M, int N, int K)
{
  __shared__ float sa[16][132];   // A tile transposed: sa[k][m]
  __shared__ float sb[16][132];   // B tile: sb[k][n]

  const int t  = threadIdx.x;
  const int n0 = blockIdx.x * 128;
  const int m0 = blockIdx.y * 128;
  const int tr = t >> 4, tc = t & 15;

  float acc[8][8];
#pragma unroll
  for (int i = 0; i < 8; i++)
#pragma unroll
    for (int j = 0; j < 8; j++) acc[i][j] = 0.f;

  const int a_m  = t >> 2;   // 0..63 (+64 on 2nd iter)
  const int a_k4 = t & 3;    // which group of 4 k
  const int b_kr = t >> 5;   // 0..7 (+8 on 2nd iter)
  const int b_n4 = t & 31;   // which float4 along n

  for (int kt = 0; kt < K; kt += 16) {
#pragma unroll
    for (int it = 0; it < 2; ++it) {
      const int m = a_m + it * 64;
      float4 av = *(const float4*)(A + (size_t)(m0 + m) * K + kt + a_k4 * 4);
      sa[a_k4 * 4 + 0][m] = av.x;
      sa[a_k4 * 4 + 1][m] = av.y;
      sa[a_k4 * 4 + 2][m] = av.z;
      sa[a_k4 * 4 + 3][m] = av.w;
      const int kr = b_kr + it * 8;
      float4 bv = *(const float4*)(Bm + (size_t)(kt + kr) * N + n0 + b_n4 * 4);
      *(float4*)&sb[kr][b_n4 * 4] = bv;
    }
    __syncthreads();
#pragma unroll
    for (int kk = 0; kk < 16; kk++) {
      float a[8], b[8];
      *(float4*)&a[0] = *(const float4*)&sa[kk][tr * 8 + 0];
      *(float4*)&a[4] = *(const float4*)&sa[kk][tr * 8 + 4];
      *(float4*)&b[0] = *(const float4*)&sb[kk][tc * 8 + 0];
      *(float4*)&b[4] = *(const float4*)&sb[kk][tc * 8 + 4];
#pragma unroll
      for (int i = 0; i < 8; i++)
#pragma unroll
        for (int j = 0; j < 8; j++)
          acc[i][j] += a[i] * b[j];
    }
    __syncthreads();
  }

#pragma unroll
  for (int i = 0; i < 8; i++) {
    const int row = m0 + tr * 8 + i;
#pragma unroll
    for (int j4 = 0; j4 < 8; j4 += 4) {
      const int col = n0 + tc * 8 + j4;
      float4 bb = *(const float4*)(bias + col);
      float4 o;
      o.x = acc[i][j4 + 0] + bb.x;
      o.y = acc[i][j4 + 1] + bb.y;
      o.z = acc[i][j4 + 2] + bb.z;
      o.w = acc[i][j4 + 3] + bb.w;
      *(float4*)(C + (size_t)row * N + col) = o;
    }
  }
}

// ---------------------------------------------------------------------------
// Fused QKV GEMM: xn[10240,512] @ {Wq|Wk|Wv}[512,512] + bias, scattered into
// q/k/v in [B,H,S,DK] layout. Each block's 128 output cols stay inside one of
// the three 512-col groups and one batch row-group, so W/bias/out resolve once.
// ---------------------------------------------------------------------------
__global__ __launch_bounds__(256) void gemm_qkv_kernel(
    const float* __restrict__ A,
    const float* __restrict__ Wq, const float* __restrict__ Wk, const float* __restrict__ Wv,
    const float* __restrict__ bq, const float* __restrict__ bk, const float* __restrict__ bv,
    float* __restrict__ q, float* __restrict__ k, float* __restrict__ v)
{
  __shared__ float sa[16][132];
  __shared__ float sb[16][132];

  const int t   = threadIdx.x;
  const int n0g = blockIdx.x * 128;          // 0..1535
  const int which = n0g >> 9;                // 0=q 1=k 2=v
  const int n0  = n0g & 511;
  const float* Bm   = (which == 0) ? Wq : (which == 1) ? Wk : Wv;
  const float* bias = (which == 0) ? bq : (which == 1) ? bk : bv;
  float* outp       = (which == 0) ? q  : (which == 1) ? k  : v;
  const int m0 = blockIdx.y * 128;
  const int tr = t >> 4, tc = t & 15;

  float acc[8][8];
#pragma unroll
  for (int i = 0; i < 8; i++)
#pragma unroll
    for (int j = 0; j < 8; j++) acc[i][j] = 0.f;

  const int a_m  = t >> 2;
  const int a_k4 = t & 3;
  const int b_kr = t >> 5;
  const int b_n4 = t & 31;

  for (int kt = 0; kt < 512; kt += 16) {
#pragma unroll
    for (int it = 0; it < 2; ++it) {
      const int m = a_m + it * 64;
      float4 av = *(const float4*)(A + (size_t)(m0 + m) * 512 + kt + a_k4 * 4);
      sa[a_k4 * 4 + 0][m] = av.x;
      sa[a_k4 * 4 + 1][m] = av.y;
      sa[a_k4 * 4 + 2][m] = av.z;
      sa[a_k4 * 4 + 3][m] = av.w;
      const int kr = b_kr + it * 8;
      float4 bv = *(const float4*)(Bm + (size_t)(kt + kr) * 512 + n0 + b_n4 * 4);
      *(float4*)&sb[kr][b_n4 * 4] = bv;
    }
    __syncthreads();
#pragma unroll
    for (int kk = 0; kk < 16; kk++) {
      float a[8], b[8];
      *(float4*)&a[0] = *(const float4*)&sa[kk][tr * 8 + 0];
      *(float4*)&a[4] = *(const float4*)&sa[kk][tr * 8 + 4];
      *(float4*)&b[0] = *(const float4*)&sb[kk][tc * 8 + 0];
      *(float4*)&b[4] = *(const float4*)&sb[kk][tc * 8 + 4];
#pragma unroll
      for (int i = 0; i < 8; i++)
#pragma unroll
        for (int j = 0; j < 8; j++)
          acc[i][j] += a[i] * b[j];
    }
    __syncthreads();
  }

#pragma unroll
  for (int i = 0; i < 8; i++) {
    const int row = m0 + tr * 8 + i;
    const int bb  = row / S_;
    const int s   = row - bb * S_;
#pragma unroll
    for (int j4 = 0; j4 < 8; j4 += 4) {
      const int col = n0 + tc * 8 + j4;     // 0..511 within this W
      const int h   = col >> 6;
      const int dk  = col & 63;
      float4 bv = *(const float4*)(bias + col);
      float4 o;
      o.x = acc[i][j4 + 0] + bv.x;
      o.y = acc[i][j4 + 1] + bv.y;
      o.z = acc[i][j4 + 2] + bv.z;
      o.w = acc[i][j4 + 3] + bv.w;
      *(float4*)(outp + ((size_t)(bb * H_ + h) * S_ + s) * DK_ + dk) = o;
    }
  }
}

// ---------------------------------------------------------------------------
// Flash-style attention, fp32. Grid (S/64, H, B), 256 threads.
// Mask is int32 (harness converts jax bool -> int32): loaded as int4,
// packed to a byte tile in LDS.
// LDS: Q^T (~17K) + one K^T/V time-shared buffer (~17K) + P (~17K)
//      + mask tile (4K) + row state (<1K)  => ~57 KB static.
// Online softmax: masked scores -> -1e30 (exp clamps to 0); fully-masked rows
// produce l=0 -> output 0, matching reference (probs zeroed at masked).
// ---------------------------------------------------------------------------
__global__ __launch_bounds__(256) void attn_kernel(
    const float* __restrict__ q, const float* __restrict__ k,
    const float* __restrict__ v, const int* __restrict__ mask,
    float* __restrict__ attn)
{
  __shared__ float sqT[64 * 68];           // sqT[d][qi]
  __shared__ float skv[64 * 68];           // K phase: skv[d][kj]; V phase: skv[kj][d]
  __shared__ float s_p[64 * 68];           // scores/probs [qi][kj]
  __shared__ unsigned char s_mask[64 * 64];
  __shared__ float s_m[64], s_l[64], s_scale[64];

  const int t     = threadIdx.x;
  const int qt    = blockIdx.x;            // 0..39
  const int h     = blockIdx.y;
  const int bb    = blockIdx.z;
  const int qbase = qt * 64;
  const size_t head_base = (size_t)(bb * H_ + h) * S_ * DK_;

  // Load Q tile transposed: sqT[d][r]
  {
    const int r = t >> 4, d4 = t & 15;
#pragma unroll
    for (int it = 0; it < 4; ++it) {
      const int rr = r + it * 16;
      float4 qv = *(const float4*)(q + head_base + (size_t)(qbase + rr) * DK_ + d4 * 4);
      sqT[(d4 * 4 + 0) * 68 + rr] = qv.x;
      sqT[(d4 * 4 + 1) * 68 + rr] = qv.y;
      sqT[(d4 * 4 + 2) * 68 + rr] = qv.z;
      sqT[(d4 * 4 + 3) * 68 + rr] = qv.w;
    }
  }
  if (t < 64) { s_m[t] = -INFINITY; s_l[t] = 0.f; }

  const int tr = t >> 4, tc = t & 15;      // 16x16 grid of 4x4 microtiles
  float accO[4][4];
#pragma unroll
  for (int i = 0; i < 4; i++)
#pragma unroll
    for (int j = 0; j < 4; j++) accO[i][j] = 0.f;

  for (int kt = 0; kt < S_; kt += 64) {
    __syncthreads();  // prev phase3 done with skv/s_p; first iter: Q ready

    // Load K tile transposed + mask tile (int32 -> byte)
    {
      const int r = t >> 4, d4 = t & 15;
#pragma unroll
      for (int it = 0; it < 4; ++it) {
        const int rr = r + it * 16;
        float4 kv = *(const float4*)(k + head_base + (size_t)(kt + rr) * DK_ + d4 * 4);
        skv[(d4 * 4 + 0) * 68 + rr] = kv.x;
        skv[(d4 * 4 + 1) * 68 + rr] = kv.y;
        skv[(d4 * 4 + 2) * 68 + rr] = kv.z;
        skv[(d4 * 4 + 3) * 68 + rr] = kv.w;
      }
#pragma unroll
      for (int it = 0; it < 4; ++it) {
        const int lin = t + it * 256;      // 0..1023
        const int mr = lin >> 4, mc4 = lin & 15;
        int4 mv = *(const int4*)(mask + (size_t)(bb * S_ + qbase + mr) * S_ + kt + mc4 * 4);
        uint32_t packed = (mv.x ? 1u : 0u) | (mv.y ? 1u << 8 : 0u) |
                          (mv.z ? 1u << 16 : 0u) | (mv.w ? 1u << 24 : 0u);
        *(uint32_t*)&s_mask[mr * 64 + mc4 * 4] = packed;
      }
    }
    __syncthreads();

    // Phase 1: scores = Q K^T / 8, mask -> -1e30
    {
      float accS[4][4];
#pragma unroll
      for (int i = 0; i < 4; i++)
#pragma unroll
        for (int j = 0; j < 4; j++) accS[i][j] = 0.f;
      for (int d = 0; d < 64; d++) {
        float a[4], b[4];
        *(float4*)a = *(const float4*)&sqT[d * 68 + tr * 4];
        *(float4*)b = *(const float4*)&skv[d * 68 + tc * 4];
#pragma unroll
        for (int i = 0; i < 4; i++)
#pragma unroll
          for (int j = 0; j < 4; j++)
            accS[i][j] += a[i] * b[j];
      }
#pragma unroll
      for (int i = 0; i < 4; i++) {
        float4 o;
#pragma unroll
        for (int j = 0; j < 4; j++) {
          const unsigned char mc = s_mask[(tr * 4 + i) * 64 + tc * 4 + j];
          ((float*)&o)[j] = mc ? -1e30f : accS[i][j] * 0.125f;
        }
        *(float4*)&s_p[(tr * 4 + i) * 68 + tc * 4] = o;
      }
    }
    __syncthreads();

    // Load V into skv (row-major) — independent of phase 2 (reads only s_p)
    {
      const int r = t >> 4, d4 = t & 15;
#pragma unroll
      for (int it = 0; it < 4; ++it) {
        const int rr = r + it * 16;
        float4 vv = *(const float4*)(v + head_base + (size_t)(kt + rr) * DK_ + d4 * 4);
        *(float4*)&skv[rr * 68 + d4 * 4] = vv;
      }
    }

    // Phase 2: online softmax update (4 lanes per row)
    {
      const int r = t >> 2, g = t & 3;
      float vals[16];
      float mloc = -INFINITY;
#pragma unroll
      for (int j = 0; j < 16; j++) {
        vals[j] = s_p[r * 68 + g + 4 * j];
        mloc = fmaxf(mloc, vals[j]);
      }
      mloc = fmaxf(mloc, __shfl_xor(mloc, 1));
      mloc = fmaxf(mloc, __shfl_xor(mloc, 2));
      const float m_old = s_m[r];
      const float m_new = fmaxf(m_old, mloc);
      const float scl = __expf(m_old - m_new);  // m_old=-inf first tile -> 0
      float psum = 0.f;
#pragma unroll
      for (int j = 0; j < 16; j++) {
        const float pv = (vals[j] <= -1e29f) ? 0.f : __expf(vals[j] - m_new);
        s_p[r * 68 + g + 4 * j] = pv;
        psum += pv;
      }
      psum += __shfl_xor(psum, 1);
      psum += __shfl_xor(psum, 2);
      if (g == 0) {
        s_m[r] = m_new;
        s_l[r] = s_l[r] * scl + psum;
        s_scale[r] = scl;
      }
    }
    __syncthreads();

    // Phase 3: rescale accumulators, accO += P @ V
#pragma unroll
    for (int i = 0; i < 4; i++) {
      const float sc = s_scale[tr * 4 + i];
#pragma unroll
      for (int j = 0; j < 4; j++) accO[i][j] *= sc;
    }
    for (int kj = 0; kj < 64; kj++) {
      float4 v4 = *(const float4*)&skv[kj * 68 + tc * 4];
#pragma unroll
      for (int i = 0; i < 4; i++) {
        const float p = s_p[(tr * 4 + i) * 68 + kj];
        accO[i][0] += p * v4.x;
        accO[i][1] += p * v4.y;
        accO[i][2] += p * v4.z;
        accO[i][3] += p * v4.w;
      }
    }
  }
  __syncthreads();

  // Write attn in [B,S,D] layout at columns h*64 + tc*4
#pragma unroll
  for (int i = 0; i < 4; i++) {
    const int qi = tr * 4 + i;
    const float l = s_l[qi];
    const float inv = (l > 0.f) ? 1.f / l : 0.f;
    float4 o;
    o.x = accO[i][0] * inv;
    o.y = accO[i][1] * inv;
    o.z = accO[i][2] * inv;
    o.w = accO[i][3] * inv;
    *(float4*)(attn + (size_t)(bb * S_ + qbase + qi) * D_ + h * DK_ + tc * 4) = o;
  }
}

// ---------------------------------------------------------------------------
// Orchestration. Workspace layout (floats), C = NTOK*D = 5,242,880:
//   xn[0,C) q[C,2C) k[2C,3C) v[3C,4C) attn[4C,5C) aout[5C,6C)
//   h1 aliases xn (safe: LN reads res[idx] before writing out[idx], same thread)
//   f aliases [C,5C) (q/k/v/attn dead after step 4)
//   g2 aliases [0,C) (h1 dead after step 5)
// Peak ws = 6C floats = 125.8 MB.
// ---------------------------------------------------------------------------
extern "C" void kernel_launch(void* const* d_in, const int* in_sizes, int n_in,
                              void* d_out, int out_size, void* d_ws, size_t ws_size,
                              hipStream_t stream)
{
  const float* x        = (const float*)d_in[0];
  const int*   mask     = (const int*)d_in[1];   // jax bool -> int32 on device
  const float* ln_in_g  = (const float*)d_in[2];
  const float* ln_in_b  = (const float*)d_in[3];
  const float* Wq       = (const float*)d_in[4];
  const float* bq       = (const float*)d_in[5];
  const float* Wk       = (const float*)d_in[6];
  const float* bk       = (const float*)d_in[7];
  const float* Wv       = (const float*)d_in[8];
  const float* bv       = (const float*)d_in[9];
  const float* ln1_g    = (const float*)d_in[10];
  const float* ln1_b    = (const float*)d_in[11];
  const float* W1       = (const float*)d_in[12];
  const float* b1       = (const float*)d_in[13];
  const float* W2       = (const float*)d_in[14];
  const float* b2       = (const float*)d_in[15];
  const float* ln2_g    = (const float*)d_in[16];
  const float* ln2_b    = (const float*)d_in[17];
  float* out = (float*)d_out;

  float* ws = (float*)d_ws;
  const size_t C = (size_t)NTOK * D_;
  float* xn   = ws + 0 * C;
  float* q    = ws + 1 * C;
  float* k    = ws + 2 * C;
  float* v    = ws + 3 * C;
  float* attn = ws + 4 * C;
  float* aout = ws + 5 * C;
  float* h1   = ws + 0 * C;   // aliases xn (dead after step 4's per-elem read)
  float* f    = ws + 1 * C;   // NTOK*F = 4C floats, reuses q/k/v/attn
  float* g2   = ws + 0 * C;   // reuses h1 slot

  // 1) xn = LN(x)
  ln_kernel<<<NTOK, 256, 0, stream>>>(x, nullptr, ln_in_g, ln_in_b, xn, nullptr);
  // 2) q,k,v = xn @ Wq/Wk/Wv + b   (written in [B,H,S,DK])
  gemm_qkv_kernel<<<dim3(1536 / 128, NTOK / 128), 256, 0, stream>>>(
      xn, Wq, Wk, Wv, bq, bk, bv, q, k, v);
  // 3) attn = softmax(mask(QK^T/8)) @ V   -> [B,S,D]
  attn_kernel<<<dim3(S_ / 64, H_, B_), 256, 0, stream>>>(q, k, v, mask, attn);
  // 4) aout = attn + xn ; h1 = LN(aout)   (h1 aliases xn)
  ln_kernel<<<NTOK, 256, 0, stream>>>(attn, xn, ln1_g, ln1_b, h1, aout);
  // 5) f = h1 @ W1 + b1
  gemm_bias_kernel<<<dim3(F_ / 128, NTOK / 128), 256, 0, stream>>>(
      h1, W1, b1, f, NTOK, F_, D_);
  // 6) g2 = f @ W2 + b2
  gemm_bias_kernel<<<dim3(D_ / 128, NTOK / 128), 256, 0, stream>>>(
      f, W2, b2, g2, NTOK, D_, F_);
  // 7) out = LN(g2 + aout)
  ln_kernel<<<NTOK, 256, 0, stream>>>(g2, aout, ln2_g, ln2_b, out, nullptr);
}

// Round 4
// 1197.415 us; speedup vs baseline: 1.5877x; 1.5877x over previous
//
#include <hip/hip_runtime.h>
#include <cstdint>
#include <cstddef>

// Problem constants (EmformerBlock): B=4, S=2560, D=512, H=8, DK=64, F=2048
#define B_    4
#define S_    2560
#define D_    512
#define H_    8
#define DK_   64
#define F_    2048
#define NTOK  (B_ * S_)   // 10240

typedef __attribute__((ext_vector_type(8))) short bf16x8;
typedef __attribute__((ext_vector_type(4))) float f32x4;
#define MFMA16(a, b, c) __builtin_amdgcn_mfma_f32_16x16x32_bf16(a, b, c, 0, 0, 0)

__device__ __forceinline__ unsigned short f2bf(float x) {  // RNE float->bf16
  unsigned int u = __float_as_uint(x);
  u += 0x7fffu + ((u >> 16) & 1u);
  return (unsigned short)(u >> 16);
}

// ---------------------------------------------------------------------------
// LayerNorm over D=512, one row per block (256 threads, 2 floats/thread).
// `out` may alias `res` (per-thread elementwise read-before-write).
// ---------------------------------------------------------------------------
__global__ __launch_bounds__(256) void ln_kernel(
    const float* __restrict__ in, const float* __restrict__ res,
    const float* __restrict__ gamma, const float* __restrict__ beta,
    float* __restrict__ out, float* __restrict__ pre_out)
{
  const int row = blockIdx.x;
  const int t   = threadIdx.x;
  const size_t base = (size_t)row * D_;

  float2 v = *(const float2*)(in + base + t * 2);
  if (res) {
    float2 r = *(const float2*)(res + base + t * 2);
    v.x += r.x; v.y += r.y;
  }
  if (pre_out) *(float2*)(pre_out + base + t * 2) = v;

  float s1 = v.x + v.y;
  float s2 = v.x * v.x + v.y * v.y;
#pragma unroll
  for (int off = 32; off > 0; off >>= 1) {
    s1 += __shfl_down(s1, off);
    s2 += __shfl_down(s2, off);
  }
  __shared__ float a1[4], a2[4];
  const int wid = t >> 6, lane = t & 63;
  if (lane == 0) { a1[wid] = s1; a2[wid] = s2; }
  __syncthreads();
  const float S1 = a1[0] + a1[1] + a1[2] + a1[3];
  const float S2 = a2[0] + a2[1] + a2[2] + a2[3];
  const float mu  = S1 * (1.0f / D_);
  const float var = S2 * (1.0f / D_) - mu * mu;
  const float inv = rsqrtf(var + 1e-5f);

  float2 g = *(const float2*)(gamma + t * 2);
  float2 b = *(const float2*)(beta  + t * 2);
  float2 o;
  o.x = (v.x - mu) * inv * g.x + b.x;
  o.y = (v.y - mu) * inv * g.y + b.y;
  *(float2*)(out + base + t * 2) = o;
}

// ---------------------------------------------------------------------------
// Generic fp32 tiled GEMM (FFN): C[M,N] = A[M,K] @ Bm[K,N] + bias[N]
// ---------------------------------------------------------------------------
__global__ __launch_bounds__(256) void gemm_bias_kernel(
    const float* __restrict__ A, const float* __restrict__ Bm,
    const float* __restrict__ bias, float* __restrict__ C,
    int M, int N, int K)
{
  __shared__ float sa[16][132];
  __shared__ float sb[16][132];

  const int t  = threadIdx.x;
  const int n0 = blockIdx.x * 128;
  const int m0 = blockIdx.y * 128;
  const int tr = t >> 4, tc = t & 15;

  float acc[8][8];
#pragma unroll
  for (int i = 0; i < 8; i++)
#pragma unroll
    for (int j = 0; j < 8; j++) acc[i][j] = 0.f;

  const int a_m  = t >> 2;
  const int a_k4 = t & 3;
  const int b_kr = t >> 5;
  const int b_n4 = t & 31;

  for (int kt = 0; kt < K; kt += 16) {
#pragma unroll
    for (int it = 0; it < 2; ++it) {
      const int m = a_m + it * 64;
      float4 av = *(const float4*)(A + (size_t)(m0 + m) * K + kt + a_k4 * 4);
      sa[a_k4 * 4 + 0][m] = av.x;
      sa[a_k4 * 4 + 1][m] = av.y;
      sa[a_k4 * 4 + 2][m] = av.z;
      sa[a_k4 * 4 + 3][m] = av.w;
      const int kr = b_kr + it * 8;
      float4 bv = *(const float4*)(Bm + (size_t)(kt + kr) * N + n0 + b_n4 * 4);
      *(float4*)&sb[kr][b_n4 * 4] = bv;
    }
    __syncthreads();
#pragma unroll
    for (int kk = 0; kk < 16; kk++) {
      float a[8], b[8];
      *(float4*)&a[0] = *(const float4*)&sa[kk][tr * 8 + 0];
      *(float4*)&a[4] = *(const float4*)&sa[kk][tr * 8 + 4];
      *(float4*)&b[0] = *(const float4*)&sb[kk][tc * 8 + 0];
      *(float4*)&b[4] = *(const float4*)&sb[kk][tc * 8 + 4];
#pragma unroll
      for (int i = 0; i < 8; i++)
#pragma unroll
        for (int j = 0; j < 8; j++)
          acc[i][j] += a[i] * b[j];
    }
    __syncthreads();
  }

#pragma unroll
  for (int i = 0; i < 8; i++) {
    const int row = m0 + tr * 8 + i;
#pragma unroll
    for (int j4 = 0; j4 < 8; j4 += 4) {
      const int col = n0 + tc * 8 + j4;
      float4 bb = *(const float4*)(bias + col);
      float4 o;
      o.x = acc[i][j4 + 0] + bb.x;
      o.y = acc[i][j4 + 1] + bb.y;
      o.z = acc[i][j4 + 2] + bb.z;
      o.w = acc[i][j4 + 3] + bb.w;
      *(float4*)(C + (size_t)row * N + col) = o;
    }
  }
}

// ---------------------------------------------------------------------------
// Fused QKV GEMM (fp32 compute), epilogue emits bf16:
//   q,k -> [B,H,S,DK] bf16 (packed ushort4 stores)
//   v   -> VT [B,H,DK,S] bf16 (scalar scatter; one-time cost, makes the
//          attention PV operand a contiguous 16B fragment)
// ---------------------------------------------------------------------------
__global__ __launch_bounds__(256) void gemm_qkv_kernel(
    const float* __restrict__ A,
    const float* __restrict__ Wq, const float* __restrict__ Wk, const float* __restrict__ Wv,
    const float* __restrict__ bq, const float* __restrict__ bk, const float* __restrict__ bv,
    unsigned short* __restrict__ qb, unsigned short* __restrict__ kb,
    unsigned short* __restrict__ vtb)
{
  __shared__ float sa[16][132];
  __shared__ float sb[16][132];

  const int t   = threadIdx.x;
  const int n0g = blockIdx.x * 128;          // 0..1408
  const int which = n0g >> 9;                // 0=q 1=k 2=v
  const int n0  = n0g & 511;
  const float* Bm   = (which == 0) ? Wq : (which == 1) ? Wk : Wv;
  const float* bias = (which == 0) ? bq : (which == 1) ? bk : bv;
  const int m0 = blockIdx.y * 128;
  const int tr = t >> 4, tc = t & 15;

  float acc[8][8];
#pragma unroll
  for (int i = 0; i < 8; i++)
#pragma unroll
    for (int j = 0; j < 8; j++) acc[i][j] = 0.f;

  const int a_m  = t >> 2;
  const int a_k4 = t & 3;
  const int b_kr = t >> 5;
  const int b_n4 = t & 31;

  for (int kt = 0; kt < 512; kt += 16) {
#pragma unroll
    for (int it = 0; it < 2; ++it) {
      const int m = a_m + it * 64;
      float4 av = *(const float4*)(A + (size_t)(m0 + m) * 512 + kt + a_k4 * 4);
      sa[a_k4 * 4 + 0][m] = av.x;
      sa[a_k4 * 4 + 1][m] = av.y;
      sa[a_k4 * 4 + 2][m] = av.z;
      sa[a_k4 * 4 + 3][m] = av.w;
      const int kr = b_kr + it * 8;
      float4 bv4 = *(const float4*)(Bm + (size_t)(kt + kr) * 512 + n0 + b_n4 * 4);
      *(float4*)&sb[kr][b_n4 * 4] = bv4;
    }
    __syncthreads();
#pragma unroll
    for (int kk = 0; kk < 16; kk++) {
      float a[8], b[8];
      *(float4*)&a[0] = *(const float4*)&sa[kk][tr * 8 + 0];
      *(float4*)&a[4] = *(const float4*)&sa[kk][tr * 8 + 4];
      *(float4*)&b[0] = *(const float4*)&sb[kk][tc * 8 + 0];
      *(float4*)&b[4] = *(const float4*)&sb[kk][tc * 8 + 4];
#pragma unroll
      for (int i = 0; i < 8; i++)
#pragma unroll
        for (int j = 0; j < 8; j++)
          acc[i][j] += a[i] * b[j];
    }
    __syncthreads();
  }

#pragma unroll
  for (int i = 0; i < 8; i++) {
    const int row = m0 + tr * 8 + i;
    const int bb  = row / S_;
    const int s   = row - bb * S_;
    if (which < 2) {
      unsigned short* outp = (which == 0) ? qb : kb;
#pragma unroll
      for (int j4 = 0; j4 < 8; j4 += 4) {
        const int col = n0 + tc * 8 + j4;
        const int hh  = col >> 6;
        const int dk  = col & 63;
        float4 bv4 = *(const float4*)(bias + col);
        ushort4 o;
        o.x = f2bf(acc[i][j4 + 0] + bv4.x);
        o.y = f2bf(acc[i][j4 + 1] + bv4.y);
        o.z = f2bf(acc[i][j4 + 2] + bv4.z);
        o.w = f2bf(acc[i][j4 + 3] + bv4.w);
        *(ushort4*)(outp + ((size_t)(bb * H_ + hh) * S_ + s) * DK_ + dk) = o;
      }
    } else {
#pragma unroll
      for (int j = 0; j < 8; j++) {
        const int col = n0 + tc * 8 + j;
        const int hh  = col >> 6;
        const int dk  = col & 63;
        vtb[((size_t)(bb * H_ + hh) * DK_ + dk) * S_ + s] = f2bf(acc[i][j] + bias[col]);
      }
    }
  }
}

// ---------------------------------------------------------------------------
// MFMA flash attention (bf16 inputs, fp32 accum). Grid (S/64, H, B), 256 thr.
// Swapped QK^T: each wave w owns qi-strip [16w,16w+16); per KV tile (64):
//   S^T tiles = mfma(K_frag, Q_frag) -> lane holds (qi=lane&15, kj=4*(l>>4)+reg)
//   softmax fully per-lane (+2 shfl_xor row-reduce), P -> LDS bf16
//   O^T tiles = mfma(VT_frag, P_frag) -> lane holds (qi=lane&15, d=4*(l>>4)+reg)
// All MFMA operands are contiguous 16B fragments; LDS XOR-swizzled
// (byte ^= (row&7)<<4) so row-strided fragment reads are conflict-free.
// LDS: K 8K + VT 8K + P 4x2K = 24 KB.
// ---------------------------------------------------------------------------
__global__ __launch_bounds__(256) void attn_mfma_kernel(
    const unsigned short* __restrict__ q, const unsigned short* __restrict__ k,
    const unsigned short* __restrict__ vt, const int* __restrict__ mask,
    float* __restrict__ attn)
{
  __shared__ __align__(16) char kT[64 * 128];     // K tile  [kj][d] bf16, swizzled
  __shared__ __align__(16) char vT[64 * 128];     // VT tile [d][kj] bf16, swizzled
  __shared__ __align__(16) char pT[4 * 16 * 128]; // per-wave P [qi][kj] bf16, swizzled

  const int t    = threadIdx.x;
  const int w    = t >> 6;
  const int lane = t & 63;
  const int lg   = lane >> 4;     // lane group 0..3
  const int lr   = lane & 15;     // fragment row
  const int qt = blockIdx.x, h = blockIdx.y, bb = blockIdx.z;
  const int qbase = qt * 64;
  const size_t hb  = (size_t)(bb * H_ + h) * S_ * DK_;  // q/k element base
  const size_t vtb = (size_t)(bb * H_ + h) * DK_ * S_;  // vt element base

  // Q fragments for this wave's qi-strip, held in registers all loop long.
  const int qi_g = qbase + w * 16 + lr;
  bf16x8 qf0 = *(const bf16x8*)(q + hb + (size_t)qi_g * DK_ + 0  + lg * 8);
  bf16x8 qf1 = *(const bf16x8*)(q + hb + (size_t)qi_g * DK_ + 32 + lg * 8);

  const int* mrow = mask + ((size_t)bb * S_ + qi_g) * S_;
  char* myP = pT + w * 2048;

  float m_run = -INFINITY, l_run = 0.f;
  f32x4 accO[4];
#pragma unroll
  for (int dt = 0; dt < 4; ++dt) accO[dt] = (f32x4){0.f, 0.f, 0.f, 0.f};

  for (int kt = 0; kt < S_; kt += 64) {
    __syncthreads();   // prev tile's K/VT fragment reads complete

    // Stage K and VT tiles (2x 16B chunks each per thread), swizzled.
#pragma unroll
    for (int it = 0; it < 2; ++it) {
      const int c   = t + it * 256;      // 0..511
      const int row = c >> 3, col = c & 7;
      int4 kv = *(const int4*)(k + hb + (size_t)(kt + row) * DK_ + col * 8);
      *(int4*)(kT + ((row * 128 + col * 16) ^ ((row & 7) << 4))) = kv;
      int4 vv = *(const int4*)(vt + vtb + (size_t)row * S_ + kt + col * 8);
      *(int4*)(vT + ((row * 128 + col * 16) ^ ((row & 7) << 4))) = vv;
    }
    // Mask straight to registers: lane needs kj = 16*t4 + 4*lg + r.
    int mm[16];
#pragma unroll
    for (int t4 = 0; t4 < 4; ++t4)
      *(int4*)&mm[t4 * 4] = *(const int4*)(mrow + kt + t4 * 16 + lg * 4);
    __syncthreads();   // staging visible

    // QK^T: 4 S^T tiles (kj0 = 16*t4), K=64 via 2 mfma each.
    float sv[16];
#pragma unroll
    for (int t4 = 0; t4 < 4; ++t4) {
      const int kjr = t4 * 16 + lr;
      const int sw  = (kjr & 7) << 4;
      f32x4 acc = (f32x4){0.f, 0.f, 0.f, 0.f};
      bf16x8 a0 = *(const bf16x8*)(kT + ((kjr * 128 + 0  + lg * 16) ^ sw));
      acc = MFMA16(a0, qf0, acc);
      bf16x8 a1 = *(const bf16x8*)(kT + ((kjr * 128 + 64 + lg * 16) ^ sw));
      acc = MFMA16(a1, qf1, acc);
      *(f32x4*)&sv[t4 * 4] = acc;
    }

    // Mask + scale; online softmax per lane (qi = lr), row-reduce via shfl.
    float s[16];
#pragma unroll
    for (int j = 0; j < 16; ++j)
      s[j] = mm[j] ? -1e30f : sv[j] * 0.125f;
    float mx = s[0];
#pragma unroll
    for (int j = 1; j < 16; ++j) mx = fmaxf(mx, s[j]);
    mx = fmaxf(mx, __shfl_xor(mx, 16));
    mx = fmaxf(mx, __shfl_xor(mx, 32));
    const float m_new = fmaxf(m_run, mx);
    const float scl = __expf(m_run - m_new);   // first tile: exp(-inf)=0
    float p[16], ts = 0.f;
#pragma unroll
    for (int j = 0; j < 16; ++j) {
      p[j] = (s[j] <= -1e29f) ? 0.f : __expf(s[j] - m_new);
      ts += p[j];
    }
    ts += __shfl_xor(ts, 16);
    ts += __shfl_xor(ts, 32);
    l_run = l_run * scl + ts;
    m_run = m_new;
#pragma unroll
    for (int dt = 0; dt < 4; ++dt) accO[dt] *= scl;

    // P -> bf16 -> per-wave LDS [qi][kj] (b64 packed, swizzled).
#pragma unroll
    for (int t4 = 0; t4 < 4; ++t4) {
      short4 pv;
      pv.x = (short)f2bf(p[t4 * 4 + 0]);
      pv.y = (short)f2bf(p[t4 * 4 + 1]);
      pv.z = (short)f2bf(p[t4 * 4 + 2]);
      pv.w = (short)f2bf(p[t4 * 4 + 3]);
      *(short4*)(myP + ((lr * 128 + t4 * 32 + lg * 8) ^ ((lr & 7) << 4))) = pv;
    }

    // PV: O^T tiles accumulate; A = VT fragment, B = P fragment.
#pragma unroll
    for (int c = 0; c < 2; ++c) {
      bf16x8 pb = *(const bf16x8*)(myP + ((lr * 128 + c * 64 + lg * 16) ^ ((lr & 7) << 4)));
#pragma unroll
      for (int dt = 0; dt < 4; ++dt) {
        const int dr = dt * 16 + lr;
        bf16x8 va = *(const bf16x8*)(vT + ((dr * 128 + c * 64 + lg * 16) ^ ((dr & 7) << 4)));
        accO[dt] = MFMA16(va, pb, accO[dt]);
      }
    }
  }

  // Epilogue: O[qi][d] / l, lane holds qi = lr, d = 16*dt + 4*lg + reg.
  const float inv = (l_run > 0.f) ? 1.f / l_run : 0.f;
#pragma unroll
  for (int dt = 0; dt < 4; ++dt) {
    float4 o;
    o.x = accO[dt][0] * inv;
    o.y = accO[dt][1] * inv;
    o.z = accO[dt][2] * inv;
    o.w = accO[dt][3] * inv;
    *(float4*)(attn + ((size_t)bb * S_ + qbase + w * 16 + lr) * D_
               + h * DK_ + dt * 16 + lg * 4) = o;
  }
}

// ---------------------------------------------------------------------------
// Workspace (floats), C = NTOK*D = 5,242,880. Peak 6C = 125.8 MB (as before).
//   xn/h1/g2 [0,C)   aout [C,2C)   qkv-bf16 [2C,3.5C)   attn [3.5C,4.5C)
//   f [2C,6C) (4C floats; overlaps qkv+attn, both dead by step 5)
// ---------------------------------------------------------------------------
extern "C" void kernel_launch(void* const* d_in, const int* in_sizes, int n_in,
                              void* d_out, int out_size, void* d_ws, size_t ws_size,
                              hipStream_t stream)
{
  const float* x        = (const float*)d_in[0];
  const int*   mask     = (const int*)d_in[1];   // jax bool -> int32 on device
  const float* ln_in_g  = (const float*)d_in[2];
  const float* ln_in_b  = (const float*)d_in[3];
  const float* Wq       = (const float*)d_in[4];
  const float* bq       = (const float*)d_in[5];
  const float* Wk       = (const float*)d_in[6];
  const float* bk       = (const float*)d_in[7];
  const float* Wv       = (const float*)d_in[8];
  const float* bv       = (const float*)d_in[9];
  const float* ln1_g    = (const float*)d_in[10];
  const float* ln1_b    = (const float*)d_in[11];
  const float* W1       = (const float*)d_in[12];
  const float* b1       = (const float*)d_in[13];
  const float* W2       = (const float*)d_in[14];
  const float* b2       = (const float*)d_in[15];
  const float* ln2_g    = (const float*)d_in[16];
  const float* ln2_b    = (const float*)d_in[17];
  float* out = (float*)d_out;

  float* ws = (float*)d_ws;
  const size_t C = (size_t)NTOK * D_;
  float* xn   = ws;                              // [0,C)
  float* aout = ws + C;                          // [C,2C)
  unsigned short* qb  = (unsigned short*)(ws + 2 * C);  // [2C,2.5C)
  unsigned short* kb  = qb + C;                  // [2.5C,3C)
  unsigned short* vtb = kb + C;                  // [3C,3.5C)
  float* attn = ws + 3 * C + C / 2;              // [3.5C,4.5C)
  float* f    = ws + 2 * C;                      // [2C,6C)
  float* h1   = ws;                              // alias xn
  float* g2   = ws;                              // alias h1 slot

  // 1) xn = LN(x)
  ln_kernel<<<NTOK, 256, 0, stream>>>(x, nullptr, ln_in_g, ln_in_b, xn, nullptr);
  // 2) q,k (bf16 [B,H,S,DK]) and vt (bf16 [B,H,DK,S]) = xn @ W + b
  gemm_qkv_kernel<<<dim3(1536 / 128, NTOK / 128), 256, 0, stream>>>(
      xn, Wq, Wk, Wv, bq, bk, bv, qb, kb, vtb);
  // 3) attn = softmax(mask(QK^T/8)) @ V   -> [B,S,D] fp32
  attn_mfma_kernel<<<dim3(S_ / 64, H_, B_), 256, 0, stream>>>(
      qb, kb, vtb, mask, attn);
  // 4) aout = attn + xn ; h1 = LN(aout)   (h1 aliases xn)
  ln_kernel<<<NTOK, 256, 0, stream>>>(attn, xn, ln1_g, ln1_b, h1, aout);
  // 5) f = h1 @ W1 + b1
  gemm_bias_kernel<<<dim3(F_ / 128, NTOK / 128), 256, 0, stream>>>(
      h1, W1, b1, f, NTOK, F_, D_);
  // 6) g2 = f @ W2 + b2
  gemm_bias_kernel<<<dim3(D_ / 128, NTOK / 128), 256, 0, stream>>>(
      f, W2, b2, g2, NTOK, D_, F_);
  // 7) out = LN(g2 + aout)
  ln_kernel<<<NTOK, 256, 0, stream>>>(g2, aout, ln2_g, ln2_b, out, nullptr);
}

// Round 10
// 534.075 us; speedup vs baseline: 3.5598x; 2.2420x over previous
//
#include <hip/hip_runtime.h>
#include <cstdint>
#include <cstddef>

// Problem constants (EmformerBlock): B=4, S=2560, D=512, H=8, DK=64, F=2048
#define B_    4
#define S_    2560
#define D_    512
#define H_    8
#define DK_   64
#define F_    2048
#define NTOK  (B_ * S_)   // 10240

typedef __attribute__((ext_vector_type(8))) short bf16x8;
typedef __attribute__((ext_vector_type(4))) float f32x4;
#define MFMA16(a, b, c) __builtin_amdgcn_mfma_f32_16x16x32_bf16(a, b, c, 0, 0, 0)

__device__ __forceinline__ unsigned short f2bf(float x) {  // RNE float->bf16
  unsigned int u = __float_as_uint(x);
  u += 0x7fffu + ((u >> 16) & 1u);
  return (unsigned short)(u >> 16);
}

// ---------------------------------------------------------------------------
// LayerNorm over D=512, one row per block. Optional residual add, optional
// fp32 out, optional bf16 out, optional fp32 pre-norm out. out may alias res.
// ---------------------------------------------------------------------------
__global__ __launch_bounds__(256) void ln_kernel(
    const float* __restrict__ in, const float* __restrict__ res,
    const float* __restrict__ gamma, const float* __restrict__ beta,
    float* __restrict__ out, unsigned short* __restrict__ outb,
    float* __restrict__ pre_out)
{
  const int row = blockIdx.x;
  const int t   = threadIdx.x;
  const size_t base = (size_t)row * D_;

  float2 v = *(const float2*)(in + base + t * 2);
  if (res) {
    float2 r = *(const float2*)(res + base + t * 2);
    v.x += r.x; v.y += r.y;
  }
  if (pre_out) *(float2*)(pre_out + base + t * 2) = v;

  float s1 = v.x + v.y;
  float s2 = v.x * v.x + v.y * v.y;
#pragma unroll
  for (int off = 32; off > 0; off >>= 1) {
    s1 += __shfl_down(s1, off);
    s2 += __shfl_down(s2, off);
  }
  __shared__ float a1[4], a2[4];
  const int wid = t >> 6, lane = t & 63;
  if (lane == 0) { a1[wid] = s1; a2[wid] = s2; }
  __syncthreads();
  const float S1 = a1[0] + a1[1] + a1[2] + a1[3];
  const float S2 = a2[0] + a2[1] + a2[2] + a2[3];
  const float mu  = S1 * (1.0f / D_);
  const float var = S2 * (1.0f / D_) - mu * mu;
  const float inv = rsqrtf(var + 1e-5f);

  float2 g = *(const float2*)(gamma + t * 2);
  float2 b = *(const float2*)(beta  + t * 2);
  float2 o;
  o.x = (v.x - mu) * inv * g.x + b.x;
  o.y = (v.y - mu) * inv * g.y + b.y;
  if (out) *(float2*)(out + base + t * 2) = o;
  if (outb) {
    ushort2 ob; ob.x = f2bf(o.x); ob.y = f2bf(o.y);
    *(ushort2*)(outb + base + t * 2) = ob;
  }
}

// ---------------------------------------------------------------------------
// Weight convert+transpose: W[K,N] fp32 -> WT[N,K] bf16. Grid (N/64, K/64).
// One-time prep; ~1% of runtime.
// ---------------------------------------------------------------------------
__global__ __launch_bounds__(256) void wconv_kernel(
    const float* __restrict__ W, unsigned short* __restrict__ WT, int K, int N)
{
  __shared__ unsigned short tp[64][80];   // stride 160B -> 16B-aligned int4 rows
  const int t  = threadIdx.x;
  const int n0 = blockIdx.x * 64, k0 = blockIdx.y * 64;
#pragma unroll
  for (int it = 0; it < 4; ++it) {
    const int r = (t >> 4) + it * 16;     // k row
    const int c = (t & 15) * 4;           // n col
    float4 wv = *(const float4*)(W + (size_t)(k0 + r) * N + n0 + c);
    tp[c + 0][r] = f2bf(wv.x);
    tp[c + 1][r] = f2bf(wv.y);
    tp[c + 2][r] = f2bf(wv.z);
    tp[c + 3][r] = f2bf(wv.w);
  }
  __syncthreads();
#pragma unroll
  for (int it = 0; it < 2; ++it) {
    const int r = (t >> 3) + it * 32;     // n row
    const int c = (t & 7) * 8;            // k col
    *(int4*)(WT + (size_t)(n0 + r) * K + k0 + c) = *(const int4*)&tp[r][c];
  }
}

// Concat bq|bk|bv into one [1536] buffer. Grid 6 x 256.
__global__ void biascat_kernel(const float* __restrict__ bq,
                               const float* __restrict__ bk,
                               const float* __restrict__ bv,
                               float* __restrict__ bc)
{
  const int t = blockIdx.x * 256 + threadIdx.x;
  bc[t] = (t < 512) ? bq[t] : (t < 1024) ? bk[t - 512] : bv[t - 1024];
}

// ---------------------------------------------------------------------------
// bf16 MFMA GEMM: C[M,N] = A[M,K] @ WT[N,K]^T + bias[N].
// 128x128 tile, BK=64, 4 waves (2x2), each wave 4x4 16x16 fragments.
// LDS 32 KB, XOR-swizzled (byte ^= (row&7)<<4) — same scheme as attention.
// MODE 0: fp32 C. MODE 1: bf16 C. MODE 2: QKV scatter (WT/bias concatenated
//   [1536][512]; q,k -> [B,H,S,DK] bf16; v -> VT [B,H,DK,S] bf16).
// ---------------------------------------------------------------------------
template <int MODE>
__global__ __launch_bounds__(256) void gemm_mfma_kernel(
    const unsigned short* __restrict__ A, const unsigned short* __restrict__ WT,
    const float* __restrict__ bias,
    float* __restrict__ Cf, unsigned short* __restrict__ Cb,
    unsigned short* __restrict__ kb, unsigned short* __restrict__ vtb,
    int M, int N, int K)
{
  __shared__ __align__(16) char sA[128 * 128];   // [m][64k] bf16, swizzled
  __shared__ __align__(16) char sW[128 * 128];   // [n][64k] bf16, swizzled

  const int t    = threadIdx.x;
  const int w    = t >> 6;
  const int lane = t & 63;
  const int lg   = lane >> 4, lr = lane & 15;
  const int wm   = w >> 1, wn = w & 1;
  const int n0 = blockIdx.x * 128;
  const int m0 = blockIdx.y * 128;

  f32x4 acc[4][4];
#pragma unroll
  for (int mi = 0; mi < 4; ++mi)
#pragma unroll
    for (int ni = 0; ni < 4; ++ni) acc[mi][ni] = (f32x4){0.f, 0.f, 0.f, 0.f};

  const int srow = t >> 3;            // 0..31 (+32/round)
  const int schk = t & 7;

  for (int kt = 0; kt < K; kt += 64) {
    __syncthreads();
#pragma unroll
    for (int it = 0; it < 4; ++it) {
      const int row = srow + it * 32;
      const int off = (row * 128 + schk * 16) ^ ((row & 7) << 4);
      *(int4*)(sA + off) =
          *(const int4*)(A + (size_t)(m0 + row) * K + kt + schk * 8);
      *(int4*)(sW + off) =
          *(const int4*)(WT + (size_t)(n0 + row) * K + kt + schk * 8);
    }
    __syncthreads();

#pragma unroll
    for (int kc = 0; kc < 2; ++kc) {
      bf16x8 af[4], wf[4];
#pragma unroll
      for (int mi = 0; mi < 4; ++mi) {
        const int row = wm * 64 + mi * 16 + lr;
        af[mi] = *(const bf16x8*)(sA + ((row * 128 + kc * 64 + lg * 16) ^ ((row & 7) << 4)));
      }
#pragma unroll
      for (int ni = 0; ni < 4; ++ni) {
        const int row = wn * 64 + ni * 16 + lr;
        wf[ni] = *(const bf16x8*)(sW + ((row * 128 + kc * 64 + lg * 16) ^ ((row & 7) << 4)));
      }
#pragma unroll
      for (int mi = 0; mi < 4; ++mi)
#pragma unroll
        for (int ni = 0; ni < 4; ++ni)
          acc[mi][ni] = MFMA16(wf[ni], af[mi], acc[mi][ni]);
    }
  }

  // Epilogue: lane holds C[m = m0+wm*64+mi*16+lr][n = n0+wn*64+ni*16+lg*4+reg]
#pragma unroll
  for (int mi = 0; mi < 4; ++mi) {
    const int m = m0 + wm * 64 + mi * 16 + lr;
#pragma unroll
    for (int ni = 0; ni < 4; ++ni) {
      const int n = n0 + wn * 64 + ni * 16 + lg * 4;
      float4 b4 = *(const float4*)(bias + n);
      const float o0 = acc[mi][ni][0] + b4.x;
      const float o1 = acc[mi][ni][1] + b4.y;
      const float o2 = acc[mi][ni][2] + b4.z;
      const float o3 = acc[mi][ni][3] + b4.w;
      if constexpr (MODE == 0) {
        float4 o = {o0, o1, o2, o3};
        *(float4*)(Cf + (size_t)m * N + n) = o;
      } else if constexpr (MODE == 1) {
        ushort4 o; o.x = f2bf(o0); o.y = f2bf(o1); o.z = f2bf(o2); o.w = f2bf(o3);
        *(ushort4*)(Cb + (size_t)m * N + n) = o;
      } else {
        const int which = n >> 9;
        const int col   = n & 511;
        const int hh = col >> 6, dk = col & 63;
        const int bb = m / S_, s = m - bb * S_;
        if (which < 2) {
          unsigned short* outp = (which == 0) ? Cb : kb;
          ushort4 o; o.x = f2bf(o0); o.y = f2bf(o1); o.z = f2bf(o2); o.w = f2bf(o3);
          *(ushort4*)(outp + ((size_t)(bb * H_ + hh) * S_ + s) * DK_ + dk) = o;
        } else {
          const size_t vb = (size_t)(bb * H_ + hh) * DK_;
          vtb[(vb + dk + 0) * S_ + s] = f2bf(o0);
          vtb[(vb + dk + 1) * S_ + s] = f2bf(o1);
          vtb[(vb + dk + 2) * S_ + s] = f2bf(o2);
          vtb[(vb + dk + 3) * S_ + s] = f2bf(o3);
        }
      }
    }
  }
}

// ---------------------------------------------------------------------------
// MFMA flash attention (bf16 inputs, fp32 accum). Grid (S/64, H, B), 256 thr.
// Unchanged from round 4 (verified): swapped QK^T, per-lane softmax,
// XOR-swizzled LDS, VT pre-transposed. LDS 24 KB.
// ---------------------------------------------------------------------------
__global__ __launch_bounds__(256) void attn_mfma_kernel(
    const unsigned short* __restrict__ q, const unsigned short* __restrict__ k,
    const unsigned short* __restrict__ vt, const int* __restrict__ mask,
    float* __restrict__ attn)
{
  __shared__ __align__(16) char kT[64 * 128];
  __shared__ __align__(16) char vT[64 * 128];
  __shared__ __align__(16) char pT[4 * 16 * 128];

  const int t    = threadIdx.x;
  const int w    = t >> 6;
  const int lane = t & 63;
  const int lg   = lane >> 4;
  const int lr   = lane & 15;
  const int qt = blockIdx.x, h = blockIdx.y, bb = blockIdx.z;
  const int qbase = qt * 64;
  const size_t hb  = (size_t)(bb * H_ + h) * S_ * DK_;
  const size_t vb  = (size_t)(bb * H_ + h) * DK_ * S_;

  const int qi_g = qbase + w * 16 + lr;
  bf16x8 qf0 = *(const bf16x8*)(q + hb + (size_t)qi_g * DK_ + 0  + lg * 8);
  bf16x8 qf1 = *(const bf16x8*)(q + hb + (size_t)qi_g * DK_ + 32 + lg * 8);

  const int* mrow = mask + ((size_t)bb * S_ + qi_g) * S_;
  char* myP = pT + w * 2048;

  float m_run = -INFINITY, l_run = 0.f;
  f32x4 accO[4];
#pragma unroll
  for (int dt = 0; dt < 4; ++dt) accO[dt] = (f32x4){0.f, 0.f, 0.f, 0.f};

  for (int kt = 0; kt < S_; kt += 64) {
    __syncthreads();

#pragma unroll
    for (int it = 0; it < 2; ++it) {
      const int c   = t + it * 256;
      const int row = c >> 3, col = c & 7;
      int4 kv = *(const int4*)(k + hb + (size_t)(kt + row) * DK_ + col * 8);
      *(int4*)(kT + ((row * 128 + col * 16) ^ ((row & 7) << 4))) = kv;
      int4 vv = *(const int4*)(vt + vb + (size_t)row * S_ + kt + col * 8);
      *(int4*)(vT + ((row * 128 + col * 16) ^ ((row & 7) << 4))) = vv;
    }
    int mm[16];
#pragma unroll
    for (int t4 = 0; t4 < 4; ++t4)
      *(int4*)&mm[t4 * 4] = *(const int4*)(mrow + kt + t4 * 16 + lg * 4);
    __syncthreads();

    float sv[16];
#pragma unroll
    for (int t4 = 0; t4 < 4; ++t4) {
      const int kjr = t4 * 16 + lr;
      const int sw  = (kjr & 7) << 4;
      f32x4 a = (f32x4){0.f, 0.f, 0.f, 0.f};
      bf16x8 a0 = *(const bf16x8*)(kT + ((kjr * 128 + 0  + lg * 16) ^ sw));
      a = MFMA16(a0, qf0, a);
      bf16x8 a1 = *(const bf16x8*)(kT + ((kjr * 128 + 64 + lg * 16) ^ sw));
      a = MFMA16(a1, qf1, a);
      *(f32x4*)&sv[t4 * 4] = a;
    }

    float s[16];
#pragma unroll
    for (int j = 0; j < 16; ++j)
      s[j] = mm[j] ? -1e30f : sv[j] * 0.125f;
    float mx = s[0];
#pragma unroll
    for (int j = 1; j < 16; ++j) mx = fmaxf(mx, s[j]);
    mx = fmaxf(mx, __shfl_xor(mx, 16));
    mx = fmaxf(mx, __shfl_xor(mx, 32));
    const float m_new = fmaxf(m_run, mx);
    const float scl = __expf(m_run - m_new);
    float p[16], ts = 0.f;
#pragma unroll
    for (int j = 0; j < 16; ++j) {
      p[j] = (s[j] <= -1e29f) ? 0.f : __expf(s[j] - m_new);
      ts += p[j];
    }
    ts += __shfl_xor(ts, 16);
    ts += __shfl_xor(ts, 32);
    l_run = l_run * scl + ts;
    m_run = m_new;
#pragma unroll
    for (int dt = 0; dt < 4; ++dt) accO[dt] *= scl;

#pragma unroll
    for (int t4 = 0; t4 < 4; ++t4) {
      short4 pv;
      pv.x = (short)f2bf(p[t4 * 4 + 0]);
      pv.y = (short)f2bf(p[t4 * 4 + 1]);
      pv.z = (short)f2bf(p[t4 * 4 + 2]);
      pv.w = (short)f2bf(p[t4 * 4 + 3]);
      *(short4*)(myP + ((lr * 128 + t4 * 32 + lg * 8) ^ ((lr & 7) << 4))) = pv;
    }

#pragma unroll
    for (int c = 0; c < 2; ++c) {
      bf16x8 pb = *(const bf16x8*)(myP + ((lr * 128 + c * 64 + lg * 16) ^ ((lr & 7) << 4)));
#pragma unroll
      for (int dt = 0; dt < 4; ++dt) {
        const int dr = dt * 16 + lr;
        bf16x8 va = *(const bf16x8*)(vT + ((dr * 128 + c * 64 + lg * 16) ^ ((dr & 7) << 4)));
        accO[dt] = MFMA16(va, pb, accO[dt]);
      }
    }
  }

  const float inv = (l_run > 0.f) ? 1.f / l_run : 0.f;
#pragma unroll
  for (int dt = 0; dt < 4; ++dt) {
    float4 o;
    o.x = accO[dt][0] * inv;
    o.y = accO[dt][1] * inv;
    o.z = accO[dt][2] * inv;
    o.w = accO[dt][3] * inv;
    *(float4*)(attn + ((size_t)bb * S_ + qbase + w * 16 + lr) * D_
               + h * DK_ + dt * 16 + lg * 4) = o;
  }
}

// ---------------------------------------------------------------------------
// Workspace (floats), C = NTOK*D = 5,242,880. Peak ~5.78C = 121 MB.
//   [0,C)      xn fp32 (later g2)
//   [C,2C)     aout fp32
//   [2C,2.5C)  xnb bf16 (later h1b)
//   [2.5C,4C)  qb,kb,vtb bf16 (later overlapped by fb)
//   [2.5C,4.5C) fb bf16 (written after q/k/vt dead)
//   [4.5C,5.5C) attn fp32
//   [5.5C,...) W1T, W2T, WqkvT (bf16), bcat (fp32)
// ---------------------------------------------------------------------------
extern "C" void kernel_launch(void* const* d_in, const int* in_sizes, int n_in,
                              void* d_out, int out_size, void* d_ws, size_t ws_size,
                              hipStream_t stream)
{
  const float* x        = (const float*)d_in[0];
  const int*   mask     = (const int*)d_in[1];   // jax bool -> int32 on device
  const float* ln_in_g  = (const float*)d_in[2];
  const float* ln_in_b  = (const float*)d_in[3];
  const float* Wq       = (const float*)d_in[4];
  const float* bq       = (const float*)d_in[5];
  const float* Wk       = (const float*)d_in[6];
  const float* bk       = (const float*)d_in[7];
  const float* Wv       = (const float*)d_in[8];
  const float* bv       = (const float*)d_in[9];
  const float* ln1_g    = (const float*)d_in[10];
  const float* ln1_b    = (const float*)d_in[11];
  const float* W1       = (const float*)d_in[12];
  const float* b1       = (const float*)d_in[13];
  const float* W2       = (const float*)d_in[14];
  const float* b2       = (const float*)d_in[15];
  const float* ln2_g    = (const float*)d_in[16];
  const float* ln2_b    = (const float*)d_in[17];
  float* out = (float*)d_out;

  float* ws = (float*)d_ws;
  const size_t C = (size_t)NTOK * D_;
  float* xn   = ws;                                    // [0,C)
  float* g2   = ws;                                    // alias (xn dead)
  float* aout = ws + C;                                // [C,2C)
  unsigned short* xnb = (unsigned short*)(ws + 2 * C); // C elems
  unsigned short* h1b = xnb;                           // alias (xnb dead)
  unsigned short* qb  = (unsigned short*)(ws + 5 * C / 2);
  unsigned short* kbuf = qb + C;
  unsigned short* vtb  = kbuf + C;
  unsigned short* fb  = (unsigned short*)(ws + 5 * C / 2);  // 4C elems, overlaps dead q/k/vt
  float* attn = ws + 9 * C / 2;                        // [4.5C,5.5C)
  unsigned short* W1T   = (unsigned short*)(ws + 11 * C / 2);      // 2048*512
  unsigned short* W2T   = W1T + (size_t)F_ * D_;                   // 512*2048
  unsigned short* WqkvT = W2T + (size_t)D_ * F_;                   // 1536*512
  float* bcat = (float*)(WqkvT + (size_t)3 * D_ * D_);             // 1536

  // 0) Weight prep (bf16 transposes) + bias concat
  wconv_kernel<<<dim3(F_ / 64, D_ / 64), 256, 0, stream>>>(W1, W1T, D_, F_);
  wconv_kernel<<<dim3(D_ / 64, F_ / 64), 256, 0, stream>>>(W2, W2T, F_, D_);
  wconv_kernel<<<dim3(8, 8), 256, 0, stream>>>(Wq, WqkvT, D_, D_);
  wconv_kernel<<<dim3(8, 8), 256, 0, stream>>>(Wk, WqkvT + (size_t)D_ * D_, D_, D_);
  wconv_kernel<<<dim3(8, 8), 256, 0, stream>>>(Wv, WqkvT + (size_t)2 * D_ * D_, D_, D_);
  biascat_kernel<<<6, 256, 0, stream>>>(bq, bk, bv, bcat);

  // 1) xn = LN(x)  (fp32 for residual, bf16 for GEMM A)
  ln_kernel<<<NTOK, 256, 0, stream>>>(x, nullptr, ln_in_g, ln_in_b, xn, xnb, nullptr);
  // 2) q,k (bf16 [B,H,S,DK]), vt (bf16 [B,H,DK,S]) via MFMA
  gemm_mfma_kernel<2><<<dim3(12, NTOK / 128), 256, 0, stream>>>(
      xnb, WqkvT, bcat, nullptr, qb, kbuf, vtb, NTOK, 1536, D_);
  // 3) attn = softmax(mask(QK^T/8)) @ V -> [B,S,D] fp32
  attn_mfma_kernel<<<dim3(S_ / 64, H_, B_), 256, 0, stream>>>(
      qb, kbuf, vtb, mask, attn);
  // 4) aout = attn + xn (fp32); h1 = LN(aout) -> bf16 only
  ln_kernel<<<NTOK, 256, 0, stream>>>(attn, xn, ln1_g, ln1_b, nullptr, h1b, aout);
  // 5) f = h1 @ W1 + b1 -> bf16
  gemm_mfma_kernel<1><<<dim3(F_ / 128, NTOK / 128), 256, 0, stream>>>(
      h1b, W1T, b1, nullptr, fb, nullptr, nullptr, NTOK, F_, D_);
  // 6) g2 = f @ W2 + b2 -> fp32
  gemm_mfma_kernel<0><<<dim3(D_ / 128, NTOK / 128), 256, 0, stream>>>(
      fb, W2T, b2, g2, nullptr, nullptr, nullptr, NTOK, D_, F_);
  // 7) out = LN(g2 + aout)
  ln_kernel<<<NTOK, 256, 0, stream>>>(g2, aout, ln2_g, ln2_b, out, nullptr, nullptr);
}